// Round 4
// baseline (572.441 us; speedup 1.0000x reference)
//
#include <hip/hip_runtime.h>

// ============================================================================
// GQA prefill: B=4, S=2048, DIM=1152, NH=8, KVH=2, HD=144, causal, start_pos=0
//
// R4 = R3 with the legacy-intrinsic spelling fixed:
//   __builtin_amdgcn_mfma_f32_16x16x16f16 (no underscore before f16).
//
// R3 changes vs R2:
//  - attn: TQ=128/block (wave owns 32 q-rows, B-frags shared across 2 row-tiles
//    -> half the LDS reads per output row); complementary work pairing
//    qi = (b<2)? x : 15-x  (stride-256 RR partner sums to uniform 34 tiles);
//    granule-swizzled LDS [kchunk][row] staged via global_load_lds (16B DMA,
//    <=2-way bank conflicts); exact d=144 (4x mfma 16x16x32 + 1x 16x16x16 tail);
//    Ps + output written as shfl-paired f16x2 (kills same-dword conflicts).
//  - gemm: global_load_lds staging + same swizzled LDS layout (old row-major
//    stride-32 B-frag reads were 8-way conflicted).
//
// ws layout (bytes):
//   x_f16    :         0 ..  18874368   (8192x1152)
//   wqkv_f16 :  18874368 ..  23003136   (1792x1152; rows>=1728 pad, discarded)
//   wo_f16   :  23003136 ..  25657344
//   bias_qkv :  25657344 ..  25664256
//   qkv f32  :  25664256 ..  82287360   (8192x1728)
//   Qh       :  82287360 .. 101161728   (4,8,2048,144) f16
//   Kh       : 101161728 .. 105880320   (4,2,2048,144) f16
//   Vt       : 105880320 .. 110598912   (4,2,144,2048) f16
//   attn_f16 : 110598912 .. 129473280   (8192x1152) f16
// ============================================================================

#define THREADS 256

typedef _Float16 f16x8 __attribute__((ext_vector_type(8)));
typedef _Float16 f16x4 __attribute__((ext_vector_type(4)));
typedef _Float16 f16x2 __attribute__((ext_vector_type(2)));
typedef float f32x4 __attribute__((ext_vector_type(4)));

// 16B global->LDS DMA: LDS dst = wave-uniform base + lane*16
#define GLDS16(gp, lp)                                                  \
  __builtin_amdgcn_global_load_lds(                                     \
      (const __attribute__((address_space(1))) unsigned int*)(gp),      \
      (__attribute__((address_space(3))) unsigned int*)(lp), 16, 0, 0)

// ---------------------------------------------------------------- cvt fp32->fp16
__global__ __launch_bounds__(THREADS) void cvt_f16(const float* __restrict__ in,
                                                   _Float16* __restrict__ out,
                                                   int n4) {
  int i = blockIdx.x * THREADS + threadIdx.x;
  if (i >= n4) return;
  float4 v = ((const float4*)in)[i];
  f16x4 o;
  o.x = (_Float16)v.x;
  o.y = (_Float16)v.y;
  o.z = (_Float16)v.z;
  o.w = (_Float16)v.w;
  ((f16x4*)out)[i] = o;
}

// ---------------------------------------------------------------- bias concat
__global__ __launch_bounds__(THREADS) void prep_bias(const float* __restrict__ bq,
                                                     const float* __restrict__ bkv,
                                                     float* __restrict__ bias) {
  int i = blockIdx.x * THREADS + threadIdx.x;
  if (i < 1152) bias[i] = bq[i];
  else if (i < 1728) bias[i] = bkv[i - 1152];
}

// ---------------------------------------------------------------- GEMM-BT fp16 MFMA
// C[m,n] = sum_k A[m,k]*B[n,k] + bias[n]. 128x128 tile, BK=32, 4 waves.
// LDS granule layout [kchunk 0..3][row 0..127] (granule = 16B = 8 f16):
// staged via global_load_lds; b128 frag reads are 2-way (free) conflicted.
__global__ __launch_bounds__(THREADS) void gemm_bt_f16(
    const _Float16* __restrict__ A, const _Float16* __restrict__ B,
    const float* __restrict__ bias, float* __restrict__ C, int M, int N, int K) {
  __shared__ __align__(16) _Float16 As[128 * 32];
  __shared__ __align__(16) _Float16 Bs[128 * 32];
  const int t = threadIdx.x;
  const int m0 = blockIdx.y << 7, n0 = blockIdx.x << 7;
  const int w = t >> 6, lane = t & 63;
  const int quad = lane >> 4, l16 = lane & 15;
  const int wm = (w & 1) << 6, wn = (w >> 1) << 6;

  f32x4 acc[4][4] = {};

  for (int k0 = 0; k0 < K; k0 += 32) {
#pragma unroll
    for (int i = 0; i < 2; ++i) {
      const int gb = (w * 2 + i) << 6;  // granule base 0,64,...,448 (64-aligned)
      const int kc = gb >> 7, r0 = gb & 127;
      GLDS16(A + (size_t)(m0 + r0 + lane) * K + k0 + kc * 8, &As[gb * 8]);
      GLDS16(B + (size_t)(n0 + r0 + lane) * K + k0 + kc * 8, &Bs[gb * 8]);
    }
    __syncthreads();
    f16x8 af[4], bf[4];
#pragma unroll
    for (int mi = 0; mi < 4; ++mi)
      af[mi] = *(const f16x8*)&As[((quad << 7) + wm + (mi << 4) + l16) * 8];
#pragma unroll
    for (int ni = 0; ni < 4; ++ni)
      bf[ni] = *(const f16x8*)&Bs[((quad << 7) + wn + (ni << 4) + l16) * 8];
#pragma unroll
    for (int mi = 0; mi < 4; ++mi)
#pragma unroll
      for (int ni = 0; ni < 4; ++ni)
        acc[mi][ni] =
            __builtin_amdgcn_mfma_f32_16x16x32_f16(af[mi], bf[ni], acc[mi][ni], 0, 0, 0);
    __syncthreads();
  }

#pragma unroll
  for (int mi = 0; mi < 4; ++mi) {
    const int row = m0 + wm + (mi << 4) + (quad << 2);
#pragma unroll
    for (int ni = 0; ni < 4; ++ni) {
      const int col = n0 + wn + (ni << 4) + l16;
      if (col < N) {
        const float bv = bias[col];
#pragma unroll
        for (int r = 0; r < 4; ++r)
          C[(size_t)(row + r) * N + col] = acc[mi][ni][r] + bv;
      }
    }
  }
}

// ---------------------------------------------------------------- RoPE -> fp16 Q/K
// qkv row (1728): [q 8x144 | k 2x144 | v 2x144]. Exact d=144 (no pad).
// 720 float2 jobs/row: 576 q-pairs + 144 k-pairs. Grid exact: 8192*720/256.
__global__ __launch_bounds__(THREADS) void rope_scatter_f16(
    const float* __restrict__ qkv, const float* __restrict__ fc,
    const float* __restrict__ fs, _Float16* __restrict__ Qh,
    _Float16* __restrict__ Kh) {
  int idx = blockIdx.x * THREADS + threadIdx.x;
  int m = idx / 720;
  int c = idx - m * 720;
  int s = m & 2047, b = m >> 11;
  const float* row = qkv + (size_t)m * 1728;
  int h, d2;
  const float* src;
  _Float16* dst;
  if (c < 576) {
    h = c / 72;
    d2 = c - h * 72;
    src = row + h * 144 + 2 * d2;
    dst = Qh + ((size_t)(b * 8 + h) * 2048 + s) * 144 + 2 * d2;
  } else {
    int cc = c - 576;
    h = cc / 72;
    d2 = cc - h * 72;
    src = row + 1152 + h * 144 + 2 * d2;
    dst = Kh + ((size_t)(b * 2 + h) * 2048 + s) * 144 + 2 * d2;
  }
  float2 v = *(const float2*)src;
  float cth = fc[s * 72 + d2], sth = fs[s * 72 + d2];
  f16x2 o;
  o.x = (_Float16)(v.x * cth - v.y * sth);
  o.y = (_Float16)(v.x * sth + v.y * cth);
  *(f16x2*)dst = o;
}

// ---------------------------------------------------------------- V transpose
// qkv V cols -> Vt[b][kvh][d:144][s:2048] fp16. Block: (stile of 128 s, kvh, b).
__global__ __launch_bounds__(THREADS) void v_transpose(const float* __restrict__ qkv,
                                                       _Float16* __restrict__ Vt) {
  __shared__ _Float16 tile[128 * 145];
  const int t = threadIdx.x;
  const int s0 = blockIdx.x * 128;
  const int kvh = blockIdx.y, b = blockIdx.z;
  const float* src = qkv + ((size_t)(b * 2048 + s0)) * 1728 + 1440 + kvh * 144;
#pragma unroll
  for (int i = 0; i < 18; ++i) {
    int c = t + i * 256;  // 128 rows x 36 float4
    int r = c / 36, cc = c - r * 36;
    float4 v = *(const float4*)(src + (size_t)r * 1728 + cc * 4);
    int base = r * 145 + cc * 4;
    tile[base + 0] = (_Float16)v.x;
    tile[base + 1] = (_Float16)v.y;
    tile[base + 2] = (_Float16)v.z;
    tile[base + 3] = (_Float16)v.w;
  }
  __syncthreads();
  _Float16* dstb = Vt + (size_t)(b * 2 + kvh) * 144 * 2048;
#pragma unroll
  for (int i = 0; i < 9; ++i) {
    int c = t + i * 256;  // 144 d x 16 s-chunks
    int d = c >> 4, sc = c & 15;
    f16x8 o;
#pragma unroll
    for (int j = 0; j < 8; ++j) o[j] = tile[(sc * 8 + j) * 145 + d];
    *(f16x8*)(dstb + (size_t)d * 2048 + s0 + sc * 8) = o;
  }
}

// ---------------------------------------------------------------- MFMA flash attention
// Block (x,h,b): TQ=128 q-rows (wave w owns rows w*32..+31 as 2 row-tiles),
// key tiles of 64. qi pairing: (b<2)? x : 15-x  -> RR partner (stride 256) is
// complementary, per-CU work uniform (34 tiles).
// LDS: Ks2 [ccol 0..17][row 0..63] granules, Vts2 [kc 0..7][d 0..143] granules,
// both DMA-staged; Ps row-major stride 72. Total 55296 B -> 2 blocks/CU.
__global__ __launch_bounds__(THREADS, 2) void attn_mfma(
    const _Float16* __restrict__ Qh, const _Float16* __restrict__ Kh,
    const _Float16* __restrict__ Vt, _Float16* __restrict__ Out) {
  __shared__ __align__(16) _Float16 Ks2[1152 * 8];
  __shared__ __align__(16) _Float16 Vts2[1152 * 8];
  __shared__ __align__(16) _Float16 Ps[128 * 72];
  const int t = threadIdx.x;
  const int w = t >> 6, lane = t & 63;
  const int quad = lane >> 4, l16 = lane & 15;
  const int h = blockIdx.y, b = blockIdx.z;
  const int qi = (b < 2) ? (int)blockIdx.x : 15 - (int)blockIdx.x;
  const int kvh = h >> 2;
  const int q0 = qi * 128;
  const _Float16* Qg = Qh + ((size_t)(b * 8 + h) * 2048 + q0) * 144;
  const _Float16* Kg = Kh + (size_t)(b * 2 + kvh) * 2048 * 144;
  const _Float16* Vg = Vt + (size_t)(b * 2 + kvh) * 144 * 2048;

  // Q fragments (registers, loaded once): rows w*32+rt*16+l16
  f16x8 qf[2][4];
  f16x4 qt4[2];
#pragma unroll
  for (int rt = 0; rt < 2; ++rt) {
    const _Float16* qp = Qg + (size_t)(w * 32 + rt * 16 + l16) * 144;
#pragma unroll
    for (int ks = 0; ks < 4; ++ks)
      qf[rt][ks] = *(const f16x8*)(qp + ks * 32 + quad * 8);
    qt4[rt] = *(const f16x4*)(qp + 128 + quad * 4);
  }

  f32x4 Oacc[2][9] = {};
  float mrow[2][4], lrow[2][4];
#pragma unroll
  for (int rt = 0; rt < 2; ++rt)
#pragma unroll
    for (int r = 0; r < 4; ++r) {
      mrow[rt][r] = -3e38f;
      lrow[rt][r] = 0.f;
    }

  const float scale = 0.08333333333333333f;  // 1/sqrt(144)
  const int nkt = qi * 2 + 2;
  for (int kt = 0; kt < nkt; ++kt) {
    // ---- stage K tile: 18 ccols x 64 rows; wave w handles ccol = w, w+4, ...
    for (int cc = w; cc < 18; cc += 4)
      GLDS16(Kg + (size_t)(kt * 64 + lane) * 144 + cc * 8, &Ks2[(cc << 6) * 8]);
    // ---- stage V tile: 8 key-chunks x 144 d; d split 64+64+16 (last predicated)
    for (int cc = w; cc < 8; cc += 4) {
#pragma unroll
      for (int db = 0; db < 3; ++db) {
        if (db < 2 || lane < 16)
          GLDS16(Vg + (size_t)(db * 64 + lane) * 2048 + kt * 64 + cc * 8,
                 &Vts2[(cc * 144 + db * 64) * 8]);
      }
    }
    __syncthreads();

    // ---- QK^T: s[rt][ct], B-frags shared across both row-tiles
    f32x4 s[2][4] = {};
#pragma unroll
    for (int ks = 0; ks < 4; ++ks) {
#pragma unroll
      for (int ct = 0; ct < 4; ++ct) {
        f16x8 bfr = *(const f16x8*)&Ks2[(((ks * 4 + quad) << 6) + ct * 16 + l16) * 8];
        s[0][ct] = __builtin_amdgcn_mfma_f32_16x16x32_f16(qf[0][ks], bfr, s[0][ct], 0, 0, 0);
        s[1][ct] = __builtin_amdgcn_mfma_f32_16x16x32_f16(qf[1][ks], bfr, s[1][ct], 0, 0, 0);
      }
    }
#pragma unroll
    for (int ct = 0; ct < 4; ++ct) {  // k=128..143 tail via legacy 16x16x16
      f16x4 bt = *(const f16x4*)&Ks2[(((16 + (quad >> 1)) << 6) + ct * 16 + l16) * 8 +
                                     (quad & 1) * 4];
      s[0][ct] = __builtin_amdgcn_mfma_f32_16x16x16f16(qt4[0], bt, s[0][ct], 0, 0, 0);
      s[1][ct] = __builtin_amdgcn_mfma_f32_16x16x16f16(qt4[1], bt, s[1][ct], 0, 0, 0);
    }

    const bool band = (kt >= nkt - 2);
    const int colb = (l16 & ~1);
    const int rsel = (lane & 1) << 1;
    // ---- online softmax per row-tile (rows quad*4+r, cols ct*16+l16)
#pragma unroll
    for (int rt = 0; rt < 2; ++rt) {
      const int rowb = q0 + w * 32 + rt * 16 + quad * 4;
      float vv[4][4];
      float mx[4] = {-3e38f, -3e38f, -3e38f, -3e38f};
#pragma unroll
      for (int ct = 0; ct < 4; ++ct) {
        const int cb = kt * 64 + ct * 16 + l16;
#pragma unroll
        for (int r = 0; r < 4; ++r) {
          float v = s[rt][ct][r] * scale;
          if (band && cb > rowb + r) v -= 1e9f;
          vv[ct][r] = v;
          mx[r] = fmaxf(mx[r], v);
        }
      }
      float alv[4];
#pragma unroll
      for (int r = 0; r < 4; ++r) {
        float m = mx[r];
        m = fmaxf(m, __shfl_xor(m, 1));
        m = fmaxf(m, __shfl_xor(m, 2));
        m = fmaxf(m, __shfl_xor(m, 4));
        m = fmaxf(m, __shfl_xor(m, 8));
        float mn = fmaxf(mrow[rt][r], m);
        alv[r] = __expf(mrow[rt][r] - mn);
        mrow[rt][r] = mn;
      }
      float rs[4] = {0.f, 0.f, 0.f, 0.f};
#pragma unroll
      for (int ct = 0; ct < 4; ++ct) {
        float p[4], q[4];
#pragma unroll
        for (int r = 0; r < 4; ++r) {
          p[r] = __expf(vv[ct][r] - mrow[rt][r]);
          rs[r] += p[r];
        }
#pragma unroll
        for (int r = 0; r < 4; ++r) q[r] = __shfl_xor(p[r], 1);
        // paired f16x2 writes: even lane rows 0,1; odd lane rows 2,3 (conflict-free)
#pragma unroll
        for (int k = 0; k < 2; ++k) {
          const int r = rsel + k;
          f16x2 pv;
          if (lane & 1) {
            pv.x = (_Float16)q[r];
            pv.y = (_Float16)p[r];
          } else {
            pv.x = (_Float16)p[r];
            pv.y = (_Float16)q[r];
          }
          *(f16x2*)&Ps[(w * 32 + rt * 16 + quad * 4 + r) * 72 + ct * 16 + colb] = pv;
        }
      }
#pragma unroll
      for (int r = 0; r < 4; ++r) {
        float v = rs[r];
        v += __shfl_xor(v, 1);
        v += __shfl_xor(v, 2);
        v += __shfl_xor(v, 4);
        v += __shfl_xor(v, 8);
        lrow[rt][r] = lrow[rt][r] * alv[r] + v;
      }
#pragma unroll
      for (int nt = 0; nt < 9; ++nt)
#pragma unroll
        for (int r = 0; r < 4; ++r) Oacc[rt][nt][r] *= alv[r];
    }

    // ---- PV: Ps strip wave-local (no barrier needed); B-frags shared across rt
#pragma unroll
    for (int ksv = 0; ksv < 2; ++ksv) {
      f16x8 pa0 = *(const f16x8*)&Ps[(w * 32 + l16) * 72 + ksv * 32 + quad * 8];
      f16x8 pa1 = *(const f16x8*)&Ps[(w * 32 + 16 + l16) * 72 + ksv * 32 + quad * 8];
#pragma unroll
      for (int nt = 0; nt < 9; ++nt) {
        f16x8 vb = *(const f16x8*)&Vts2[((ksv * 4 + quad) * 144 + nt * 16 + l16) * 8];
        Oacc[0][nt] = __builtin_amdgcn_mfma_f32_16x16x32_f16(pa0, vb, Oacc[0][nt], 0, 0, 0);
        Oacc[1][nt] = __builtin_amdgcn_mfma_f32_16x16x32_f16(pa1, vb, Oacc[1][nt], 0, 0, 0);
      }
    }
    __syncthreads();
  }

  // ---- epilogue: normalize, paired f16x2 global stores (attn matrix, fp16)
  const int colb = (l16 & ~1);
  const int rsel = (lane & 1) << 1;
#pragma unroll
  for (int rt = 0; rt < 2; ++rt) {
    float inv[4];
#pragma unroll
    for (int r = 0; r < 4; ++r) inv[r] = 1.f / lrow[rt][r];
#pragma unroll
    for (int nt = 0; nt < 9; ++nt) {
      float o[4], qn[4];
#pragma unroll
      for (int r = 0; r < 4; ++r) o[r] = Oacc[rt][nt][r] * inv[r];
#pragma unroll
      for (int r = 0; r < 4; ++r) qn[r] = __shfl_xor(o[r], 1);
#pragma unroll
      for (int k = 0; k < 2; ++k) {
        const int r = rsel + k;
        f16x2 pv;
        if (lane & 1) {
          pv.x = (_Float16)qn[r];
          pv.y = (_Float16)o[r];
        } else {
          pv.x = (_Float16)o[r];
          pv.y = (_Float16)qn[r];
        }
        const size_t rowg = (size_t)b * 2048 + q0 + w * 32 + rt * 16 + quad * 4 + r;
        *(f16x2*)&Out[rowg * 1152 + h * 144 + nt * 16 + colb] = pv;
      }
    }
  }
}

// ============================================================================
extern "C" void kernel_launch(void* const* d_in, const int* in_sizes, int n_in,
                              void* d_out, int out_size, void* d_ws, size_t ws_size,
                              hipStream_t stream) {
  const float* x = (const float*)d_in[0];
  const float* wq = (const float*)d_in[1];
  const float* bq = (const float*)d_in[2];
  const float* wkv = (const float*)d_in[3];
  const float* bkv = (const float*)d_in[4];
  const float* wo = (const float*)d_in[5];
  const float* bo = (const float*)d_in[6];
  const float* fc = (const float*)d_in[7];
  const float* fs = (const float*)d_in[8];
  // d_in[9..12] (k_cache, v_cache, mask, start_pos) unused: start_pos=0 prefill.
  float* out = (float*)d_out;
  char* ws = (char*)d_ws;

  _Float16* x_f16 = (_Float16*)(ws + 0);
  _Float16* wqkv_f16 = (_Float16*)(ws + 18874368);
  _Float16* wo_f16 = (_Float16*)(ws + 23003136);
  float* bias_qkv = (float*)(ws + 25657344);
  float* qkv = (float*)(ws + 25664256);
  _Float16* Qh = (_Float16*)(ws + 82287360);
  _Float16* Kh = (_Float16*)(ws + 101161728);
  _Float16* Vt = (_Float16*)(ws + 105880320);
  _Float16* attn_f16 = (_Float16*)(ws + 110598912);

  cvt_f16<<<9216, THREADS, 0, stream>>>(x, x_f16, 2359296);
  cvt_f16<<<1296, THREADS, 0, stream>>>(wq, wqkv_f16, 331776);
  cvt_f16<<<648, THREADS, 0, stream>>>(wkv, wqkv_f16 + 1327104, 165888);
  cvt_f16<<<1296, THREADS, 0, stream>>>(wo, wo_f16, 331776);
  prep_bias<<<7, THREADS, 0, stream>>>(bq, bkv, bias_qkv);

  gemm_bt_f16<<<dim3(14, 64), THREADS, 0, stream>>>(x_f16, wqkv_f16, bias_qkv, qkv,
                                                    8192, 1728, 1152);

  rope_scatter_f16<<<23040, THREADS, 0, stream>>>(qkv, fc, fs, Qh, Kh);
  v_transpose<<<dim3(16, 2, 4), THREADS, 0, stream>>>(qkv, Vt);

  attn_mfma<<<dim3(16, 8, 4), THREADS, 0, stream>>>(Qh, Kh, Vt, attn_f16);

  gemm_bt_f16<<<dim3(9, 64), THREADS, 0, stream>>>(attn_f16, wo_f16, bo, out, 8192,
                                                   1152, 1152);
}